// Round 12
// baseline (420.339 us; speedup 1.0000x reference)
//
#include <hip/hip_runtime.h>

#define NB 16
#define HH 256
#define WW 256
#define NPIX (HH*WW)

typedef _Float16 f16;
typedef _Float16 f16x8 __attribute__((ext_vector_type(8)));
typedef float f32x4 __attribute__((ext_vector_type(4)));

// slotted+swizzled f16 LDS tile [P][64]: slot (16B, 8 f16) index XOR'd with p&7
__device__ __forceinline__ int swzoff(int p, int c) {
    return p * 64 + ((((c >> 3) ^ (p & 7)) << 3) | (c & 7));
}

// ---------------------------------------------------------------------------
// prepack: all weights -> f16 packed.
// pA1/pA2 [64][32] k=tap(9,pad32); pWa [64][32] k=cin*9+tap(18,pad32);
// pBs1/pBs2 [16][64] tap-shifted conv1b: row=tap(9 used), col=cin;
// pWb [64][576] k=tap*64+cin; pWc [96][576] rows81-95 zero.
// ---------------------------------------------------------------------------
__global__ __launch_bounds__(256) void prepack_kernel(
    const float* __restrict__ w1a, const float* __restrict__ w2a,
    const float* __restrict__ w1b, const float* __restrict__ w2b,
    const float* __restrict__ wfa, const float* __restrict__ wfb,
    const float* __restrict__ wfc,
    f16* __restrict__ pA1, f16* __restrict__ pA2, f16* __restrict__ pWa,
    f16* __restrict__ pBs1, f16* __restrict__ pBs2,
    f16* __restrict__ pWb, f16* __restrict__ pWc)
{
    int i = blockIdx.x * 256 + threadIdx.x;
    if (i < 2048) {
        int c = i >> 5, k = i & 31;
        pA1[i] = (f16)(k < 9 ? w1a[c * 9 + k] : 0.f);
        pA2[i] = (f16)(k < 9 ? w2a[c * 9 + k] : 0.f);
        pWa[i] = (f16)(k < 18 ? wfa[c * 18 + k] : 0.f);
    }
    if (i < 1024) {
        int r = i >> 6, cin = i & 63;   // row = tap, col = cin
        pBs1[i] = (f16)(r < 9 ? w1b[cin * 9 + r] : 0.f);
        pBs2[i] = (f16)(r < 9 ? w2b[cin * 9 + r] : 0.f);
    }
    if (i < 36864) {
        int c = i / 576, k = i % 576;
        int tap = k >> 6, cin = k & 63;
        pWb[i] = (f16)wfb[(c * 64 + cin) * 9 + tap];
    }
    if (i < 55296) {
        int r = i / 576, k = i % 576;
        int tap = k >> 6, cin = k & 63;
        pWc[i] = (f16)(r < 81 ? wfc[(r * 64 + cin) * 9 + tap] : 0.f);
    }
}

// ---------------------------------------------------------------------------
// K1: branch -> feat.  (unchanged from round 11)
// ---------------------------------------------------------------------------
__global__ __launch_bounds__(256, 3) void k1_branch(
    const float* __restrict__ x, const float* __restrict__ g,
    const float* __restrict__ b1a, const float* __restrict__ b2a,
    const float* __restrict__ b1b, const float* __restrict__ b2b,
    const f16* __restrict__ pA1, const f16* __restrict__ pA2,
    const f16* __restrict__ pBs1, const f16* __restrict__ pBs2,
    float* __restrict__ feat)
{
    __shared__ f16 xt[400];       // 20x20 input tile
    __shared__ f16 hid[20736];    // [324][64] swz
    __shared__ f16 part[9 * 328]; // conv1b tap partials over 18x18 region
    __shared__ float bA[64];

    const int tid = threadIdx.x;
    const int wid = tid >> 6, lane = tid & 63;
    const int gq = lane >> 4, cl = lane & 15;
    const int x0 = blockIdx.x * 16, y0 = blockIdx.y * 16;
    const int b = blockIdx.z >> 1, br = blockIdx.z & 1;

    const float* in = (br ? g : x) + (size_t)b * NPIX;
    const f16* pA = br ? pA2 : pA1;
    const f16* pBs = br ? pBs2 : pBs1;
    const float bscal = (br ? b2b : b1b)[0];

    for (int t = tid; t < 400; t += 256) {
        int r = t / 20, c = t % 20;
        int gy = y0 - 2 + r, gx = x0 - 2 + c;
        xt[t] = (f16)(((unsigned)gy < (unsigned)HH && (unsigned)gx < (unsigned)WW)
                          ? in[gy * WW + gx] : 0.f);
    }
    if (tid < 64) bA[tid] = (br ? b2a : b1a)[tid];

    int koff[8];
    #pragma unroll
    for (int j = 0; j < 8; j++) {
        int k = gq * 8 + j;
        int kc = k < 9 ? k : 0;
        koff[j] = (kc / 3) * 20 + (kc % 3);
    }

    f16x8 afA[4];
    #pragma unroll
    for (int mt = 0; mt < 4; mt++)
        afA[mt] = *(const f16x8*)&pA[(mt * 16 + cl) * 32 + gq * 8];
    f16x8 afS0 = *(const f16x8*)&pBs[cl * 64 + gq * 8];
    f16x8 afS1 = *(const f16x8*)&pBs[cl * 64 + 32 + gq * 8];
    __syncthreads();

    // conv1a: hidden 18x18 region (static 6-iter unroll)
    #pragma unroll
    for (int it = 0; it < 6; it++) {
        int nt = wid + it * 4;
        if (nt < 21) {
            int p = nt * 16 + cl;
            int pc = p > 323 ? 323 : p;
            int py = pc / 18, px = pc - 18 * py;
            int base = py * 20 + px;
            f16x8 bf;
            #pragma unroll
            for (int j = 0; j < 8; j++) bf[j] = xt[base + koff[j]];
            int gy = y0 - 1 + py, gx = x0 - 1 + px;
            bool ok = (p < 324) &&
                      ((unsigned)gy < (unsigned)HH && (unsigned)gx < (unsigned)WW);
            #pragma unroll
            for (int mt = 0; mt < 4; mt++) {
                f32x4 z = {0.f, 0.f, 0.f, 0.f};
                f32x4 acc = __builtin_amdgcn_mfma_f32_16x16x32_f16(afA[mt], bf, z, 0, 0, 0);
                if (p < 324) {
                    int c0 = mt * 16 + gq * 4;
                    union { f16 h[4]; uint2 u2; } pk;
                    #pragma unroll
                    for (int r = 0; r < 4; r++)
                        pk.h[r] = (f16)(ok ? fmaxf(acc[r] + bA[c0 + r], 0.f) : 0.f);
                    *(uint2*)&hid[swzoff(p, c0)] = pk.u2;
                }
            }
        }
    }
    __syncthreads();

    // conv1b partials (static 6-iter unroll)
    #pragma unroll
    for (int it = 0; it < 6; it++) {
        int nt = wid + it * 4;
        if (nt < 21) {
            int p = nt * 16 + cl;
            int pc = p > 323 ? 323 : p;
            f16x8 bf0 = *(const f16x8*)&hid[swzoff(pc, gq * 8)];
            f16x8 bf1 = *(const f16x8*)&hid[swzoff(pc, 32 + gq * 8)];
            f32x4 z = {0.f, 0.f, 0.f, 0.f};
            f32x4 d = __builtin_amdgcn_mfma_f32_16x16x32_f16(afS0, bf0, z, 0, 0, 0);
            d = __builtin_amdgcn_mfma_f32_16x16x32_f16(afS1, bf1, d, 0, 0, 0);
            #pragma unroll
            for (int r = 0; r < 4; r++) {
                int tap = gq * 4 + r;
                if (tap < 9 && p < 324)
                    part[tap * 328 + p] = (f16)d[r];
            }
        }
    }
    __syncthreads();

    {
        int ty = tid >> 4, tx = tid & 15;
        float s = bscal;
        #pragma unroll
        for (int u = 0; u < 3; u++)
            #pragma unroll
            for (int v = 0; v < 3; v++)
                s += (float)part[(u * 3 + v) * 328 + (ty + u) * 18 + tx + v];
        feat[((size_t)(b * 2 + br)) * NPIX + (y0 + ty) * WW + x0 + tx] = s;
    }
}

// ---------------------------------------------------------------------------
// K2: feat -> h1 (LDS, 18x18) -> h2 (HBM f16 [ci][pix][64]).
// (unchanged from round 11: 2-kk phases + T14 async split)
// ---------------------------------------------------------------------------
__global__ __launch_bounds__(256, 3) void k2_wfab(
    const float* __restrict__ feat, const f16* __restrict__ pWa,
    const f16* __restrict__ pWb, const float* __restrict__ bfa,
    const float* __restrict__ bfb, f16* __restrict__ h2g, int b0)
{
    __shared__ f16 ftt[800];      // [2][400] feat tile 20x20
    __shared__ f16 hid[20736];    // h1 [324][64] swz
    __shared__ f16 wbufB[64 * 72];// 2-kk weight chunk, row pad 72
    __shared__ float bA[64];
    __shared__ float bB[64];

    const int tid = threadIdx.x;
    const int wid = tid >> 6, lane = tid & 63;
    const int gq = lane >> 4, cl = lane & 15;
    const int x0 = blockIdx.x * 16, y0 = blockIdx.y * 16;
    const int ci = blockIdx.z, b = b0 + ci;

    for (int t = tid; t < 800; t += 256) {
        int cin = t / 400, p = t - 400 * cin;
        int r = p / 20, c = p - 20 * r;
        int gy = y0 - 2 + r, gx = x0 - 2 + c;
        ftt[t] = (f16)(((unsigned)gy < (unsigned)HH && (unsigned)gx < (unsigned)WW)
                           ? feat[((size_t)(b * 2 + cin)) * NPIX + gy * WW + gx] : 0.f);
    }
    if (tid < 64) { bA[tid] = bfa[tid]; bB[tid] = bfb[tid]; }

    int koff[8];
    #pragma unroll
    for (int j = 0; j < 8; j++) {
        int k = gq * 8 + j;
        int kc = k < 18 ? k : 0;
        int cin = kc >= 9 ? 1 : 0;
        int tap = kc - 9 * cin;
        koff[j] = cin * 400 + (tap / 3) * 20 + (tap % 3);
    }

    f16x8 afA[4];
    #pragma unroll
    for (int mt = 0; mt < 4; mt++)
        afA[mt] = *(const f16x8*)&pWa[(mt * 16 + cl) * 32 + gq * 8];
    __syncthreads();

    // wfa: h1 18x18 (static 6-iter unroll)
    #pragma unroll
    for (int it = 0; it < 6; it++) {
        int nt = wid + it * 4;
        if (nt < 21) {
            int p = nt * 16 + cl;
            int pc = p > 323 ? 323 : p;
            int py = pc / 18, px = pc - 18 * py;
            int base = py * 20 + px;
            f16x8 bf;
            #pragma unroll
            for (int j = 0; j < 8; j++) bf[j] = ftt[base + koff[j]];
            int gy = y0 - 1 + py, gx = x0 - 1 + px;
            bool ok = (p < 324) &&
                      ((unsigned)gy < (unsigned)HH && (unsigned)gx < (unsigned)WW);
            #pragma unroll
            for (int mt = 0; mt < 4; mt++) {
                f32x4 z = {0.f, 0.f, 0.f, 0.f};
                f32x4 acc = __builtin_amdgcn_mfma_f32_16x16x32_f16(afA[mt], bf, z, 0, 0, 0);
                if (p < 324) {
                    int c0 = mt * 16 + gq * 4;
                    union { f16 h[4]; uint2 u2; } pk;
                    #pragma unroll
                    for (int r = 0; r < 4; r++)
                        pk.h[r] = (f16)(ok ? fmaxf(acc[r] + bA[c0 + r], 0.f) : 0.f);
                    *(uint2*)&hid[swzoff(p, c0)] = pk.u2;
                }
            }
        }
    }
    __syncthreads();

    // wfb: 9 tap-phases x 2 sub-kks, double-buffered via regs (T14)
    f32x4 acc[4][4];
    #pragma unroll
    for (int i = 0; i < 4; i++)
        #pragma unroll
        for (int mt = 0; mt < 4; mt++) acc[i][mt] = (f32x4){0.f, 0.f, 0.f, 0.f};

    const int wrow = tid >> 3, wcol = (tid & 7) * 8;
    f16x8 wr0 = *(const f16x8*)&pWb[wrow * 576 + wcol];
    f16x8 wr1 = *(const f16x8*)&pWb[(wrow + 32) * 576 + wcol];
    #pragma unroll 1
    for (int t = 0; t < 9; t++) {
        __syncthreads();                         // prev phase's readers done
        *(f16x8*)&wbufB[wrow * 72 + wcol] = wr0;
        *(f16x8*)&wbufB[(wrow + 32) * 72 + wcol] = wr1;
        if (t < 8) {                             // issue next chunk early
            wr0 = *(const f16x8*)&pWb[wrow * 576 + (t + 1) * 64 + wcol];
            wr1 = *(const f16x8*)&pWb[(wrow + 32) * 576 + (t + 1) * 64 + wcol];
        }
        __syncthreads();                         // writes visible
        int u = t / 3, v = t - 3 * u;            // tap = t
        #pragma unroll
        for (int sub = 0; sub < 2; sub++) {
            int c0 = sub * 32 + gq * 8;
            f16x8 af[4];
            #pragma unroll
            for (int mt = 0; mt < 4; mt++)
                af[mt] = *(const f16x8*)&wbufB[(mt * 16 + cl) * 72 + sub * 32 + gq * 8];
            #pragma unroll
            for (int i = 0; i < 4; i++) {
                int nt = wid * 4 + i;
                int hp = (nt + u) * 18 + cl + v;
                f16x8 bf = *(const f16x8*)&hid[swzoff(hp, c0)];
                #pragma unroll
                for (int mt = 0; mt < 4; mt++)
                    acc[i][mt] = __builtin_amdgcn_mfma_f32_16x16x32_f16(af[mt], bf, acc[i][mt], 0, 0, 0);
            }
        }
    }
    #pragma unroll
    for (int i = 0; i < 4; i++) {
        int nt = wid * 4 + i;                       // tile row; pixel col = cl
        size_t pb = ((size_t)ci * NPIX + (size_t)((y0 + nt) * WW + x0 + cl)) * 64;
        #pragma unroll
        for (int mt = 0; mt < 4; mt++) {
            int c0 = mt * 16 + gq * 4;
            union { f16 h[4]; uint2 u2; } pk;
            #pragma unroll
            for (int r = 0; r < 4; r++)
                pk.h[r] = (f16)fmaxf(acc[i][mt][r] + bB[c0 + r], 0.f);
            *(uint2*)&h2g[pb + c0] = pk.u2;
        }
    }
}

// ---------------------------------------------------------------------------
// K3 v2: h2 -> logits(96) -> softmax(81) -> patch apply -> out.
// 512 threads = 4 row-groups x 2 cout-halves. Each wave owns 48 couts with
// A-frags in REGISTERS (9 one-tap phases, 6 f16x8 live, unroll 1 -> no
// spill-hoist) -> ZERO barriers in the kk loop. Two-stage softmax: per-wave
// partial (m,s,o) over 48 couts -> LDS part[2][256][3] -> 1 barrier -> merge.
// launch_bounds(512,4) pins VGPR <=128 -> 16 waves/CU (vs 12).
// ---------------------------------------------------------------------------
__global__ __launch_bounds__(512, 4) void k3_wfc_apply(
    const f16* __restrict__ h2g, const f16* __restrict__ pWc,
    const float* __restrict__ bfc, const float* __restrict__ x,
    float* __restrict__ out, int b0)
{
    __shared__ f16 h2t[20736];    // [324][64] swz
    __shared__ float xt24[576];   // 24x24
    __shared__ float bC[96];
    __shared__ float part[2][256][3];

    const int tid = threadIdx.x;          // 0..511
    const int wid = tid >> 6, lane = tid & 63;
    const int gq = lane >> 4, cl = lane & 15;
    const int rg = wid >> 1;              // row group 0..3
    const int hf = wid & 1;               // cout half 0..1 (couts hf*48..+47)
    const int x0 = blockIdx.x * 16, y0 = blockIdx.y * 16;
    const int ci = blockIdx.z, b = b0 + ci;

    for (int t = tid; t < 2592; t += 512) {
        int p = t >> 3, grp = t & 7;
        int py = p / 18, px = p - 18 * py;
        int gy = y0 - 1 + py, gx = x0 - 1 + px;
        f16x8 v = {};
        if ((unsigned)gy < (unsigned)HH && (unsigned)gx < (unsigned)WW)
            v = *(const f16x8*)&h2g[((size_t)ci * NPIX + (size_t)(gy * WW + gx)) * 64 + grp * 8];
        *(f16x8*)&h2t[swzoff(p, grp * 8)] = v;
    }
    const float* xb = x + (size_t)b * NPIX;
    for (int t = tid; t < 576; t += 512) {
        int r = t / 24, c = t - 24 * r;
        int gy = y0 - 4 + r, gx = x0 - 4 + c;
        xt24[t] = ((unsigned)gy < (unsigned)HH && (unsigned)gx < (unsigned)WW)
                      ? xb[gy * WW + gx] : 0.f;
    }
    if (tid < 96) bC[tid] = tid < 81 ? bfc[tid] : 0.f;
    __syncthreads();

    // barrier-free main loop: 9 tap-phases, A-frags in regs from L2
    f32x4 acc[4][3];
    #pragma unroll
    for (int i = 0; i < 4; i++)
        #pragma unroll
        for (int mt = 0; mt < 3; mt++) acc[i][mt] = (f32x4){0.f, 0.f, 0.f, 0.f};

    const f16* wbase = pWc + ((size_t)(hf * 48 + cl)) * 576 + gq * 8;
    #pragma unroll 1
    for (int tap = 0; tap < 9; tap++) {
        int u = tap / 3, v = tap - 3 * u;
        f16x8 af[2][3];
        #pragma unroll
        for (int sub = 0; sub < 2; sub++)
            #pragma unroll
            for (int mt = 0; mt < 3; mt++)
                af[sub][mt] = *(const f16x8*)&wbase[(size_t)mt * 16 * 576
                                                   + (tap * 2 + sub) * 32];
        #pragma unroll
        for (int sub = 0; sub < 2; sub++) {
            int c0 = sub * 32 + gq * 8;
            #pragma unroll
            for (int i = 0; i < 4; i++) {
                int nt = rg * 4 + i;
                int hp = (nt + u) * 18 + cl + v;
                f16x8 bf = *(const f16x8*)&h2t[swzoff(hp, c0)];
                #pragma unroll
                for (int mt = 0; mt < 3; mt++)
                    acc[i][mt] = __builtin_amdgcn_mfma_f32_16x16x32_f16(
                        af[sub][mt], bf, acc[i][mt], 0, 0, 0);
            }
        }
    }

    // per-wave partial softmax over this half's 48 couts
    #pragma unroll
    for (int i = 0; i < 4; i++) {
        int nt = rg * 4 + i;                  // pixel row; pixel col = cl
        float val[3][4];
        float m = -1e30f;
        #pragma unroll
        for (int mt = 0; mt < 3; mt++)
            #pragma unroll
            for (int r = 0; r < 4; r++) {
                int c = hf * 48 + mt * 16 + gq * 4 + r;
                float vv = (c <= 80) ? acc[i][mt][r] + bC[c] : -1e30f;
                val[mt][r] = vv;
                m = fmaxf(m, vv);
            }
        m = fmaxf(m, __shfl_xor(m, 16));
        m = fmaxf(m, __shfl_xor(m, 32));
        float s = 0.f, o = 0.f;
        #pragma unroll
        for (int mt = 0; mt < 3; mt++)
            #pragma unroll
            for (int r = 0; r < 4; r++) {
                int c = hf * 48 + mt * 16 + gq * 4 + r;
                if (c <= 80) {
                    float e = __expf(val[mt][r] - m);
                    int u9 = c / 9, v9 = c - 9 * u9;
                    s += e;
                    o += e * xt24[(nt + u9) * 24 + cl + v9];
                }
            }
        s += __shfl_xor(s, 16); s += __shfl_xor(s, 32);
        o += __shfl_xor(o, 16); o += __shfl_xor(o, 32);
        if (gq == 0) {
            part[hf][nt * 16 + cl][0] = m;
            part[hf][nt * 16 + cl][1] = s;
            part[hf][nt * 16 + cl][2] = o;
        }
    }
    __syncthreads();

    // merge the two halves (flash-style rescale) and store
    if (tid < 256) {
        int p = tid;
        float m0 = part[0][p][0], s0 = part[0][p][1], o0 = part[0][p][2];
        float m1 = part[1][p][0], s1 = part[1][p][1], o1 = part[1][p][2];
        float m = fmaxf(m0, m1);
        float e0 = __expf(m0 - m), e1 = __expf(m1 - m);
        float s = s0 * e0 + s1 * e1;
        float o = o0 * e0 + o1 * e1;
        out[(size_t)b * NPIX + (y0 + (p >> 4)) * WW + x0 + (p & 15)] = o / s;
    }
}

// ---------------------------------------------------------------------------
extern "C" void kernel_launch(void* const* d_in, const int* in_sizes, int n_in,
                              void* d_out, int out_size, void* d_ws, size_t ws_size,
                              hipStream_t stream)
{
    const float* x   = (const float*)d_in[0];
    const float* g   = (const float*)d_in[1];
    const float* w1a = (const float*)d_in[2];  const float* b1a = (const float*)d_in[3];
    const float* w1b = (const float*)d_in[4];  const float* b1b = (const float*)d_in[5];
    const float* w2a = (const float*)d_in[6];  const float* b2a = (const float*)d_in[7];
    const float* w2b = (const float*)d_in[8];  const float* b2b = (const float*)d_in[9];
    const float* wfa = (const float*)d_in[10]; const float* bfa = (const float*)d_in[11];
    const float* wfb = (const float*)d_in[12]; const float* bfb = (const float*)d_in[13];
    const float* wfc = (const float*)d_in[14]; const float* bfc = (const float*)d_in[15];
    float* out = (float*)d_out;

    // workspace: feat f32 | h2 chunk f16 | packed weights f16
    float* feat = (float*)d_ws;                       // 2,097,152 f32
    size_t featB = 2097152ull * 4;
    size_t pkB = 100352ull * 2;
    int nbc = 16;
    while (nbc > 1 && featB + (size_t)nbc * NPIX * 64 * 2 + pkB > ws_size) nbc >>= 1;

    f16* h2g = (f16*)((char*)d_ws + featB);
    f16* pk  = h2g + (size_t)nbc * NPIX * 64;
    f16* pA1  = pk;             // 2048
    f16* pA2  = pA1 + 2048;     // 2048
    f16* pWa  = pA2 + 2048;     // 2048
    f16* pBs1 = pWa + 2048;     // 1024
    f16* pBs2 = pBs1 + 1024;    // 1024
    f16* pWb  = pBs2 + 1024;    // 36864
    f16* pWc  = pWb + 36864;    // 55296

    prepack_kernel<<<dim3(216), 256, 0, stream>>>(
        w1a, w2a, w1b, w2b, wfa, wfb, wfc, pA1, pA2, pWa, pBs1, pBs2, pWb, pWc);

    k1_branch<<<dim3(16, 16, 32), 256, 0, stream>>>(
        x, g, b1a, b2a, b1b, b2b, pA1, pA2, pBs1, pBs2, feat);

    for (int b0 = 0; b0 < NB; b0 += nbc) {
        int cn = (NB - b0) < nbc ? (NB - b0) : nbc;
        k2_wfab<<<dim3(16, 16, cn), 256, 0, stream>>>(
            feat, pWa, pWb, bfa, bfb, h2g, b0);
        k3_wfc_apply<<<dim3(16, 16, cn), 512, 0, stream>>>(
            h2g, pWc, bfc, x, out, b0);
    }
}

// Round 13
// 338.318 us; speedup vs baseline: 1.2424x; 1.2424x over previous
//
#include <hip/hip_runtime.h>

#define NB 16
#define HH 256
#define WW 256
#define NPIX (HH*WW)

typedef _Float16 f16;
typedef _Float16 f16x8 __attribute__((ext_vector_type(8)));
typedef float f32x4 __attribute__((ext_vector_type(4)));

// slotted+swizzled f16 LDS tile [P][64]: slot (16B, 8 f16) index XOR'd with p&7
__device__ __forceinline__ int swzoff(int p, int c) {
    return p * 64 + ((((c >> 3) ^ (p & 7)) << 3) | (c & 7));
}

// ---------------------------------------------------------------------------
// prepack: all weights -> f16 packed.
// pA1/pA2 [64][32] k=tap(9,pad32); pWa [64][32] k=cin*9+tap(18,pad32);
// pBs1/pBs2 [16][64] tap-shifted conv1b: row=tap(9 used), col=cin;
// pWb [64][576] k=tap*64+cin; pWc [96][576] rows81-95 zero.
// ---------------------------------------------------------------------------
__global__ __launch_bounds__(256) void prepack_kernel(
    const float* __restrict__ w1a, const float* __restrict__ w2a,
    const float* __restrict__ w1b, const float* __restrict__ w2b,
    const float* __restrict__ wfa, const float* __restrict__ wfb,
    const float* __restrict__ wfc,
    f16* __restrict__ pA1, f16* __restrict__ pA2, f16* __restrict__ pWa,
    f16* __restrict__ pBs1, f16* __restrict__ pBs2,
    f16* __restrict__ pWb, f16* __restrict__ pWc)
{
    int i = blockIdx.x * 256 + threadIdx.x;
    if (i < 2048) {
        int c = i >> 5, k = i & 31;
        pA1[i] = (f16)(k < 9 ? w1a[c * 9 + k] : 0.f);
        pA2[i] = (f16)(k < 9 ? w2a[c * 9 + k] : 0.f);
        pWa[i] = (f16)(k < 18 ? wfa[c * 18 + k] : 0.f);
    }
    if (i < 1024) {
        int r = i >> 6, cin = i & 63;   // row = tap, col = cin
        pBs1[i] = (f16)(r < 9 ? w1b[cin * 9 + r] : 0.f);
        pBs2[i] = (f16)(r < 9 ? w2b[cin * 9 + r] : 0.f);
    }
    if (i < 36864) {
        int c = i / 576, k = i % 576;
        int tap = k >> 6, cin = k & 63;
        pWb[i] = (f16)wfb[(c * 64 + cin) * 9 + tap];
    }
    if (i < 55296) {
        int r = i / 576, k = i % 576;
        int tap = k >> 6, cin = k & 63;
        pWc[i] = (f16)(r < 81 ? wfc[(r * 64 + cin) * 9 + tap] : 0.f);
    }
}

// ---------------------------------------------------------------------------
// K1: branch -> feat.  (unchanged from round 11)
// ---------------------------------------------------------------------------
__global__ __launch_bounds__(256, 3) void k1_branch(
    const float* __restrict__ x, const float* __restrict__ g,
    const float* __restrict__ b1a, const float* __restrict__ b2a,
    const float* __restrict__ b1b, const float* __restrict__ b2b,
    const f16* __restrict__ pA1, const f16* __restrict__ pA2,
    const f16* __restrict__ pBs1, const f16* __restrict__ pBs2,
    float* __restrict__ feat)
{
    __shared__ f16 xt[400];       // 20x20 input tile
    __shared__ f16 hid[20736];    // [324][64] swz
    __shared__ f16 part[9 * 328]; // conv1b tap partials over 18x18 region
    __shared__ float bA[64];

    const int tid = threadIdx.x;
    const int wid = tid >> 6, lane = tid & 63;
    const int gq = lane >> 4, cl = lane & 15;
    const int x0 = blockIdx.x * 16, y0 = blockIdx.y * 16;
    const int b = blockIdx.z >> 1, br = blockIdx.z & 1;

    const float* in = (br ? g : x) + (size_t)b * NPIX;
    const f16* pA = br ? pA2 : pA1;
    const f16* pBs = br ? pBs2 : pBs1;
    const float bscal = (br ? b2b : b1b)[0];

    for (int t = tid; t < 400; t += 256) {
        int r = t / 20, c = t % 20;
        int gy = y0 - 2 + r, gx = x0 - 2 + c;
        xt[t] = (f16)(((unsigned)gy < (unsigned)HH && (unsigned)gx < (unsigned)WW)
                          ? in[gy * WW + gx] : 0.f);
    }
    if (tid < 64) bA[tid] = (br ? b2a : b1a)[tid];

    int koff[8];
    #pragma unroll
    for (int j = 0; j < 8; j++) {
        int k = gq * 8 + j;
        int kc = k < 9 ? k : 0;
        koff[j] = (kc / 3) * 20 + (kc % 3);
    }

    f16x8 afA[4];
    #pragma unroll
    for (int mt = 0; mt < 4; mt++)
        afA[mt] = *(const f16x8*)&pA[(mt * 16 + cl) * 32 + gq * 8];
    f16x8 afS0 = *(const f16x8*)&pBs[cl * 64 + gq * 8];
    f16x8 afS1 = *(const f16x8*)&pBs[cl * 64 + 32 + gq * 8];
    __syncthreads();

    // conv1a: hidden 18x18 region (static 6-iter unroll)
    #pragma unroll
    for (int it = 0; it < 6; it++) {
        int nt = wid + it * 4;
        if (nt < 21) {
            int p = nt * 16 + cl;
            int pc = p > 323 ? 323 : p;
            int py = pc / 18, px = pc - 18 * py;
            int base = py * 20 + px;
            f16x8 bf;
            #pragma unroll
            for (int j = 0; j < 8; j++) bf[j] = xt[base + koff[j]];
            int gy = y0 - 1 + py, gx = x0 - 1 + px;
            bool ok = (p < 324) &&
                      ((unsigned)gy < (unsigned)HH && (unsigned)gx < (unsigned)WW);
            #pragma unroll
            for (int mt = 0; mt < 4; mt++) {
                f32x4 z = {0.f, 0.f, 0.f, 0.f};
                f32x4 acc = __builtin_amdgcn_mfma_f32_16x16x32_f16(afA[mt], bf, z, 0, 0, 0);
                if (p < 324) {
                    int c0 = mt * 16 + gq * 4;
                    union { f16 h[4]; uint2 u2; } pk;
                    #pragma unroll
                    for (int r = 0; r < 4; r++)
                        pk.h[r] = (f16)(ok ? fmaxf(acc[r] + bA[c0 + r], 0.f) : 0.f);
                    *(uint2*)&hid[swzoff(p, c0)] = pk.u2;
                }
            }
        }
    }
    __syncthreads();

    // conv1b partials (static 6-iter unroll)
    #pragma unroll
    for (int it = 0; it < 6; it++) {
        int nt = wid + it * 4;
        if (nt < 21) {
            int p = nt * 16 + cl;
            int pc = p > 323 ? 323 : p;
            f16x8 bf0 = *(const f16x8*)&hid[swzoff(pc, gq * 8)];
            f16x8 bf1 = *(const f16x8*)&hid[swzoff(pc, 32 + gq * 8)];
            f32x4 z = {0.f, 0.f, 0.f, 0.f};
            f32x4 d = __builtin_amdgcn_mfma_f32_16x16x32_f16(afS0, bf0, z, 0, 0, 0);
            d = __builtin_amdgcn_mfma_f32_16x16x32_f16(afS1, bf1, d, 0, 0, 0);
            #pragma unroll
            for (int r = 0; r < 4; r++) {
                int tap = gq * 4 + r;
                if (tap < 9 && p < 324)
                    part[tap * 328 + p] = (f16)d[r];
            }
        }
    }
    __syncthreads();

    {
        int ty = tid >> 4, tx = tid & 15;
        float s = bscal;
        #pragma unroll
        for (int u = 0; u < 3; u++)
            #pragma unroll
            for (int v = 0; v < 3; v++)
                s += (float)part[(u * 3 + v) * 328 + (ty + u) * 18 + tx + v];
        feat[((size_t)(b * 2 + br)) * NPIX + (y0 + ty) * WW + x0 + tx] = s;
    }
}

// ---------------------------------------------------------------------------
// K2: feat -> h1 (LDS, 18x18) -> h2 (HBM f16 [ci][pix][64]).
// (unchanged from round 11: 2-kk phases + T14 async split)
// ---------------------------------------------------------------------------
__global__ __launch_bounds__(256, 3) void k2_wfab(
    const float* __restrict__ feat, const f16* __restrict__ pWa,
    const f16* __restrict__ pWb, const float* __restrict__ bfa,
    const float* __restrict__ bfb, f16* __restrict__ h2g, int b0)
{
    __shared__ f16 ftt[800];      // [2][400] feat tile 20x20
    __shared__ f16 hid[20736];    // h1 [324][64] swz
    __shared__ f16 wbufB[64 * 72];// 2-kk weight chunk, row pad 72
    __shared__ float bA[64];
    __shared__ float bB[64];

    const int tid = threadIdx.x;
    const int wid = tid >> 6, lane = tid & 63;
    const int gq = lane >> 4, cl = lane & 15;
    const int x0 = blockIdx.x * 16, y0 = blockIdx.y * 16;
    const int ci = blockIdx.z, b = b0 + ci;

    for (int t = tid; t < 800; t += 256) {
        int cin = t / 400, p = t - 400 * cin;
        int r = p / 20, c = p - 20 * r;
        int gy = y0 - 2 + r, gx = x0 - 2 + c;
        ftt[t] = (f16)(((unsigned)gy < (unsigned)HH && (unsigned)gx < (unsigned)WW)
                           ? feat[((size_t)(b * 2 + cin)) * NPIX + gy * WW + gx] : 0.f);
    }
    if (tid < 64) { bA[tid] = bfa[tid]; bB[tid] = bfb[tid]; }

    int koff[8];
    #pragma unroll
    for (int j = 0; j < 8; j++) {
        int k = gq * 8 + j;
        int kc = k < 18 ? k : 0;
        int cin = kc >= 9 ? 1 : 0;
        int tap = kc - 9 * cin;
        koff[j] = cin * 400 + (tap / 3) * 20 + (tap % 3);
    }

    f16x8 afA[4];
    #pragma unroll
    for (int mt = 0; mt < 4; mt++)
        afA[mt] = *(const f16x8*)&pWa[(mt * 16 + cl) * 32 + gq * 8];
    __syncthreads();

    // wfa: h1 18x18 (static 6-iter unroll)
    #pragma unroll
    for (int it = 0; it < 6; it++) {
        int nt = wid + it * 4;
        if (nt < 21) {
            int p = nt * 16 + cl;
            int pc = p > 323 ? 323 : p;
            int py = pc / 18, px = pc - 18 * py;
            int base = py * 20 + px;
            f16x8 bf;
            #pragma unroll
            for (int j = 0; j < 8; j++) bf[j] = ftt[base + koff[j]];
            int gy = y0 - 1 + py, gx = x0 - 1 + px;
            bool ok = (p < 324) &&
                      ((unsigned)gy < (unsigned)HH && (unsigned)gx < (unsigned)WW);
            #pragma unroll
            for (int mt = 0; mt < 4; mt++) {
                f32x4 z = {0.f, 0.f, 0.f, 0.f};
                f32x4 acc = __builtin_amdgcn_mfma_f32_16x16x32_f16(afA[mt], bf, z, 0, 0, 0);
                if (p < 324) {
                    int c0 = mt * 16 + gq * 4;
                    union { f16 h[4]; uint2 u2; } pk;
                    #pragma unroll
                    for (int r = 0; r < 4; r++)
                        pk.h[r] = (f16)(ok ? fmaxf(acc[r] + bA[c0 + r], 0.f) : 0.f);
                    *(uint2*)&hid[swzoff(p, c0)] = pk.u2;
                }
            }
        }
    }
    __syncthreads();

    // wfb: 9 tap-phases x 2 sub-kks, double-buffered via regs (T14)
    f32x4 acc[4][4];
    #pragma unroll
    for (int i = 0; i < 4; i++)
        #pragma unroll
        for (int mt = 0; mt < 4; mt++) acc[i][mt] = (f32x4){0.f, 0.f, 0.f, 0.f};

    const int wrow = tid >> 3, wcol = (tid & 7) * 8;
    f16x8 wr0 = *(const f16x8*)&pWb[wrow * 576 + wcol];
    f16x8 wr1 = *(const f16x8*)&pWb[(wrow + 32) * 576 + wcol];
    #pragma unroll 1
    for (int t = 0; t < 9; t++) {
        __syncthreads();                         // prev phase's readers done
        *(f16x8*)&wbufB[wrow * 72 + wcol] = wr0;
        *(f16x8*)&wbufB[(wrow + 32) * 72 + wcol] = wr1;
        if (t < 8) {                             // issue next chunk early
            wr0 = *(const f16x8*)&pWb[wrow * 576 + (t + 1) * 64 + wcol];
            wr1 = *(const f16x8*)&pWb[(wrow + 32) * 576 + (t + 1) * 64 + wcol];
        }
        __syncthreads();                         // writes visible
        int u = t / 3, v = t - 3 * u;            // tap = t
        #pragma unroll
        for (int sub = 0; sub < 2; sub++) {
            int c0 = sub * 32 + gq * 8;
            f16x8 af[4];
            #pragma unroll
            for (int mt = 0; mt < 4; mt++)
                af[mt] = *(const f16x8*)&wbufB[(mt * 16 + cl) * 72 + sub * 32 + gq * 8];
            #pragma unroll
            for (int i = 0; i < 4; i++) {
                int nt = wid * 4 + i;
                int hp = (nt + u) * 18 + cl + v;
                f16x8 bf = *(const f16x8*)&hid[swzoff(hp, c0)];
                #pragma unroll
                for (int mt = 0; mt < 4; mt++)
                    acc[i][mt] = __builtin_amdgcn_mfma_f32_16x16x32_f16(af[mt], bf, acc[i][mt], 0, 0, 0);
            }
        }
    }
    #pragma unroll
    for (int i = 0; i < 4; i++) {
        int nt = wid * 4 + i;                       // tile row; pixel col = cl
        size_t pb = ((size_t)ci * NPIX + (size_t)((y0 + nt) * WW + x0 + cl)) * 64;
        #pragma unroll
        for (int mt = 0; mt < 4; mt++) {
            int c0 = mt * 16 + gq * 4;
            union { f16 h[4]; uint2 u2; } pk;
            #pragma unroll
            for (int r = 0; r < 4; r++)
                pk.h[r] = (f16)fmaxf(acc[i][mt][r] + bB[c0 + r], 0.f);
            *(uint2*)&h2g[pb + c0] = pk.u2;
        }
    }
}

// ---------------------------------------------------------------------------
// K3 v3: h2 -> logits(96) -> softmax(81) -> patch apply -> out.
// Round-11 LDS weight staging RESTORED (round-12's scattered global af loads
// regressed: MfmaUtil 33->19). New: DOUBLE-BUFFERED wbufC with ONE barrier
// per kk (iter kk writes chunk kk+1 into buf^1 — its readers finished before
// the previous barrier). Barriers 36 -> 19. 512 threads (8 waves x 2 rows,
// acc[2][6]) so 2 blocks/CU x 8 waves = 16 waves/CU (vs 12). Softmax stays
// single-stage (wave owns all 96 couts of its rows).
// ---------------------------------------------------------------------------
__global__ __launch_bounds__(512, 4) void k3_wfc_apply(
    const f16* __restrict__ h2g, const f16* __restrict__ pWc,
    const float* __restrict__ bfc, const float* __restrict__ x,
    float* __restrict__ out, int b0)
{
    __shared__ f16 h2t[20736];       // [324][64] swz
    __shared__ f16 wbufC[2][96 * 36];// double-buffered per-kk weight chunk
    __shared__ float xt24[576];      // 24x24
    __shared__ float bC[96];

    const int tid = threadIdx.x;     // 0..511
    const int wid = tid >> 6, lane = tid & 63;
    const int gq = lane >> 4, cl = lane & 15;
    const int x0 = blockIdx.x * 16, y0 = blockIdx.y * 16;
    const int ci = blockIdx.z, b = b0 + ci;

    for (int t = tid; t < 2592; t += 512) {
        int p = t >> 3, grp = t & 7;
        int py = p / 18, px = p - 18 * py;
        int gy = y0 - 1 + py, gx = x0 - 1 + px;
        f16x8 v = {};
        if ((unsigned)gy < (unsigned)HH && (unsigned)gx < (unsigned)WW)
            v = *(const f16x8*)&h2g[((size_t)ci * NPIX + (size_t)(gy * WW + gx)) * 64 + grp * 8];
        *(f16x8*)&h2t[swzoff(p, grp * 8)] = v;
    }
    const float* xb = x + (size_t)b * NPIX;
    for (int t = tid; t < 576; t += 512) {
        int r = t / 24, c = t - 24 * r;
        int gy = y0 - 4 + r, gx = x0 - 4 + c;
        xt24[t] = ((unsigned)gy < (unsigned)HH && (unsigned)gx < (unsigned)WW)
                      ? xb[gy * WW + gx] : 0.f;
    }
    if (tid < 96) bC[tid] = tid < 81 ? bfc[tid] : 0.f;

    // prologue: stage chunk 0 into buf 0, prefetch chunk 1 to regs
    const int crow = tid >> 2, ccol = (tid & 3) * 8;   // tid<384 covers 96 rows
    f16x8 wr = {};
    if (tid < 384) {
        *(f16x8*)&wbufC[0][crow * 36 + ccol] =
            *(const f16x8*)&pWc[crow * 576 + ccol];
        wr = *(const f16x8*)&pWc[crow * 576 + 32 + ccol];
    }
    __syncthreads();

    f32x4 acc[2][6];
    #pragma unroll
    for (int i = 0; i < 2; i++)
        #pragma unroll
        for (int mt = 0; mt < 6; mt++) acc[i][mt] = (f32x4){0.f, 0.f, 0.f, 0.f};

    #pragma unroll 1
    for (int kk = 0; kk < 18; kk++) {
        int buf = kk & 1;
        // write next chunk into the other buffer; prefetch chunk kk+2
        if (kk + 1 < 18 && tid < 384) {
            *(f16x8*)&wbufC[buf ^ 1][crow * 36 + ccol] = wr;
            if (kk + 2 < 18)
                wr = *(const f16x8*)&pWc[crow * 576 + (kk + 2) * 32 + ccol];
        }
        int tap = kk >> 1;
        int u = tap / 3, v = tap - 3 * u;
        int c0 = (kk & 1) * 32 + gq * 8;
        f16x8 af[6];
        #pragma unroll
        for (int mt = 0; mt < 6; mt++)
            af[mt] = *(const f16x8*)&wbufC[buf][(mt * 16 + cl) * 36 + gq * 8];
        #pragma unroll
        for (int i = 0; i < 2; i++) {
            int nt = wid * 2 + i;
            int hp = (nt + u) * 18 + cl + v;
            f16x8 bf = *(const f16x8*)&h2t[swzoff(hp, c0)];
            #pragma unroll
            for (int mt = 0; mt < 6; mt++)
                acc[i][mt] = __builtin_amdgcn_mfma_f32_16x16x32_f16(af[mt], bf, acc[i][mt], 0, 0, 0);
        }
        __syncthreads();   // buf^1 writes visible; buf reads done before overwrite
    }

    // softmax over taps (rows) for each pixel (col=cl); reduce across gq lanes
    #pragma unroll
    for (int i = 0; i < 2; i++) {
        int nt = wid * 2 + i;                       // pixel row; pixel col = cl
        float val[6][4];
        float m = -1e30f;
        #pragma unroll
        for (int mt = 0; mt < 6; mt++)
            #pragma unroll
            for (int r = 0; r < 4; r++) {
                int c = mt * 16 + gq * 4 + r;
                float vv = (c <= 80) ? acc[i][mt][r] + bC[c] : -1e30f;
                val[mt][r] = vv;
                m = fmaxf(m, vv);
            }
        m = fmaxf(m, __shfl_xor(m, 16));
        m = fmaxf(m, __shfl_xor(m, 32));
        float s = 0.f, o = 0.f;
        #pragma unroll
        for (int mt = 0; mt < 6; mt++)
            #pragma unroll
            for (int r = 0; r < 4; r++) {
                int c = mt * 16 + gq * 4 + r;
                if (c <= 80) {
                    float e = __expf(val[mt][r] - m);
                    int u9 = c / 9, v9 = c - 9 * u9;
                    s += e;
                    o += e * xt24[(nt + u9) * 24 + cl + v9];
                }
            }
        s += __shfl_xor(s, 16); s += __shfl_xor(s, 32);
        o += __shfl_xor(o, 16); o += __shfl_xor(o, 32);
        if (gq == 0)
            out[(size_t)b * NPIX + (y0 + nt) * WW + x0 + cl] = o / s;
    }
}

// ---------------------------------------------------------------------------
extern "C" void kernel_launch(void* const* d_in, const int* in_sizes, int n_in,
                              void* d_out, int out_size, void* d_ws, size_t ws_size,
                              hipStream_t stream)
{
    const float* x   = (const float*)d_in[0];
    const float* g   = (const float*)d_in[1];
    const float* w1a = (const float*)d_in[2];  const float* b1a = (const float*)d_in[3];
    const float* w1b = (const float*)d_in[4];  const float* b1b = (const float*)d_in[5];
    const float* w2a = (const float*)d_in[6];  const float* b2a = (const float*)d_in[7];
    const float* w2b = (const float*)d_in[8];  const float* b2b = (const float*)d_in[9];
    const float* wfa = (const float*)d_in[10]; const float* bfa = (const float*)d_in[11];
    const float* wfb = (const float*)d_in[12]; const float* bfb = (const float*)d_in[13];
    const float* wfc = (const float*)d_in[14]; const float* bfc = (const float*)d_in[15];
    float* out = (float*)d_out;

    // workspace: feat f32 | h2 chunk f16 | packed weights f16
    float* feat = (float*)d_ws;                       // 2,097,152 f32
    size_t featB = 2097152ull * 4;
    size_t pkB = 100352ull * 2;
    int nbc = 16;
    while (nbc > 1 && featB + (size_t)nbc * NPIX * 64 * 2 + pkB > ws_size) nbc >>= 1;

    f16* h2g = (f16*)((char*)d_ws + featB);
    f16* pk  = h2g + (size_t)nbc * NPIX * 64;
    f16* pA1  = pk;             // 2048
    f16* pA2  = pA1 + 2048;     // 2048
    f16* pWa  = pA2 + 2048;     // 2048
    f16* pBs1 = pWa + 2048;     // 1024
    f16* pBs2 = pBs1 + 1024;    // 1024
    f16* pWb  = pBs2 + 1024;    // 36864
    f16* pWc  = pWb + 36864;    // 55296

    prepack_kernel<<<dim3(216), 256, 0, stream>>>(
        w1a, w2a, w1b, w2b, wfa, wfb, wfc, pA1, pA2, pWa, pBs1, pBs2, pWb, pWc);

    k1_branch<<<dim3(16, 16, 32), 256, 0, stream>>>(
        x, g, b1a, b2a, b1b, b2b, pA1, pA2, pBs1, pBs2, feat);

    for (int b0 = 0; b0 < NB; b0 += nbc) {
        int cn = (NB - b0) < nbc ? (NB - b0) : nbc;
        k2_wfab<<<dim3(16, 16, cn), 256, 0, stream>>>(
            feat, pWa, pWb, bfa, bfb, h2g, b0);
        k3_wfc_apply<<<dim3(16, 16, cn), 512, 0, stream>>>(
            h2g, pWc, bfc, x, out, b0);
    }
}

// Round 14
// 321.933 us; speedup vs baseline: 1.3057x; 1.0509x over previous
//
#include <hip/hip_runtime.h>

#define NB 16
#define HH 256
#define WW 256
#define NPIX (HH*WW)

typedef _Float16 f16;
typedef _Float16 f16x8 __attribute__((ext_vector_type(8)));
typedef float f32x4 __attribute__((ext_vector_type(4)));

// slotted+swizzled f16 LDS tile [P][64]: slot (16B, 8 f16) index XOR'd with p&7
__device__ __forceinline__ int swzoff(int p, int c) {
    return p * 64 + ((((c >> 3) ^ (p & 7)) << 3) | (c & 7));
}

// ---------------------------------------------------------------------------
// prepack: all weights -> f16 packed.
// pA1/pA2 [64][32] k=tap(9,pad32); pWa [64][32] k=cin*9+tap(18,pad32);
// pBs1/pBs2 [16][64] tap-shifted conv1b: row=tap(9 used), col=cin;
// pWbF [18][4][512] FRAGMENT-major wfb: elem (kk,mt,l,j) = W[mt*16+(l&15)]
//   [k=kk*32+(l>>4)*8+j]  -> af load = coalesced 1KB global_load_dwordx4;
// pWcF [18][6][512] fragment-major wfc (couts>=81 zero).
// ---------------------------------------------------------------------------
__global__ __launch_bounds__(256) void prepack_kernel(
    const float* __restrict__ w1a, const float* __restrict__ w2a,
    const float* __restrict__ w1b, const float* __restrict__ w2b,
    const float* __restrict__ wfa, const float* __restrict__ wfb,
    const float* __restrict__ wfc,
    f16* __restrict__ pA1, f16* __restrict__ pA2, f16* __restrict__ pWa,
    f16* __restrict__ pBs1, f16* __restrict__ pBs2,
    f16* __restrict__ pWbF, f16* __restrict__ pWcF)
{
    int i = blockIdx.x * 256 + threadIdx.x;
    if (i < 2048) {
        int c = i >> 5, k = i & 31;
        pA1[i] = (f16)(k < 9 ? w1a[c * 9 + k] : 0.f);
        pA2[i] = (f16)(k < 9 ? w2a[c * 9 + k] : 0.f);
        pWa[i] = (f16)(k < 18 ? wfa[c * 18 + k] : 0.f);
    }
    if (i < 1024) {
        int r = i >> 6, cin = i & 63;   // row = tap, col = cin
        pBs1[i] = (f16)(r < 9 ? w1b[cin * 9 + r] : 0.f);
        pBs2[i] = (f16)(r < 9 ? w2b[cin * 9 + r] : 0.f);
    }
    if (i < 36864) {            // pWbF [18][4][512]
        int kk = i / 2048, r = i & 2047;
        int mt = r >> 9, e = r & 511;
        int l = e >> 3, j = e & 7;
        int cout = mt * 16 + (l & 15);
        int k = kk * 32 + ((l >> 4) << 3) + j;
        int tap = k >> 6, cin = k & 63;
        pWbF[i] = (f16)wfb[(cout * 64 + cin) * 9 + tap];
    }
    if (i < 55296) {            // pWcF [18][6][512]
        int kk = i / 3072, r = i % 3072;
        int mt = r >> 9, e = r & 511;
        int l = e >> 3, j = e & 7;
        int cout = mt * 16 + (l & 15);
        int k = kk * 32 + ((l >> 4) << 3) + j;
        int tap = k >> 6, cin = k & 63;
        pWcF[i] = (f16)(cout < 81 ? wfc[(cout * 64 + cin) * 9 + tap] : 0.f);
    }
}

// ---------------------------------------------------------------------------
// K1: branch -> feat.  (unchanged from round 11/13)
// ---------------------------------------------------------------------------
__global__ __launch_bounds__(256, 3) void k1_branch(
    const float* __restrict__ x, const float* __restrict__ g,
    const float* __restrict__ b1a, const float* __restrict__ b2a,
    const float* __restrict__ b1b, const float* __restrict__ b2b,
    const f16* __restrict__ pA1, const f16* __restrict__ pA2,
    const f16* __restrict__ pBs1, const f16* __restrict__ pBs2,
    float* __restrict__ feat)
{
    __shared__ f16 xt[400];       // 20x20 input tile
    __shared__ f16 hid[20736];    // [324][64] swz
    __shared__ f16 part[9 * 328]; // conv1b tap partials over 18x18 region
    __shared__ float bA[64];

    const int tid = threadIdx.x;
    const int wid = tid >> 6, lane = tid & 63;
    const int gq = lane >> 4, cl = lane & 15;
    const int x0 = blockIdx.x * 16, y0 = blockIdx.y * 16;
    const int b = blockIdx.z >> 1, br = blockIdx.z & 1;

    const float* in = (br ? g : x) + (size_t)b * NPIX;
    const f16* pA = br ? pA2 : pA1;
    const f16* pBs = br ? pBs2 : pBs1;
    const float bscal = (br ? b2b : b1b)[0];

    for (int t = tid; t < 400; t += 256) {
        int r = t / 20, c = t % 20;
        int gy = y0 - 2 + r, gx = x0 - 2 + c;
        xt[t] = (f16)(((unsigned)gy < (unsigned)HH && (unsigned)gx < (unsigned)WW)
                          ? in[gy * WW + gx] : 0.f);
    }
    if (tid < 64) bA[tid] = (br ? b2a : b1a)[tid];

    int koff[8];
    #pragma unroll
    for (int j = 0; j < 8; j++) {
        int k = gq * 8 + j;
        int kc = k < 9 ? k : 0;
        koff[j] = (kc / 3) * 20 + (kc % 3);
    }

    f16x8 afA[4];
    #pragma unroll
    for (int mt = 0; mt < 4; mt++)
        afA[mt] = *(const f16x8*)&pA[(mt * 16 + cl) * 32 + gq * 8];
    f16x8 afS0 = *(const f16x8*)&pBs[cl * 64 + gq * 8];
    f16x8 afS1 = *(const f16x8*)&pBs[cl * 64 + 32 + gq * 8];
    __syncthreads();

    // conv1a: hidden 18x18 region (static 6-iter unroll)
    #pragma unroll
    for (int it = 0; it < 6; it++) {
        int nt = wid + it * 4;
        if (nt < 21) {
            int p = nt * 16 + cl;
            int pc = p > 323 ? 323 : p;
            int py = pc / 18, px = pc - 18 * py;
            int base = py * 20 + px;
            f16x8 bf;
            #pragma unroll
            for (int j = 0; j < 8; j++) bf[j] = xt[base + koff[j]];
            int gy = y0 - 1 + py, gx = x0 - 1 + px;
            bool ok = (p < 324) &&
                      ((unsigned)gy < (unsigned)HH && (unsigned)gx < (unsigned)WW);
            #pragma unroll
            for (int mt = 0; mt < 4; mt++) {
                f32x4 z = {0.f, 0.f, 0.f, 0.f};
                f32x4 acc = __builtin_amdgcn_mfma_f32_16x16x32_f16(afA[mt], bf, z, 0, 0, 0);
                if (p < 324) {
                    int c0 = mt * 16 + gq * 4;
                    union { f16 h[4]; uint2 u2; } pk;
                    #pragma unroll
                    for (int r = 0; r < 4; r++)
                        pk.h[r] = (f16)(ok ? fmaxf(acc[r] + bA[c0 + r], 0.f) : 0.f);
                    *(uint2*)&hid[swzoff(p, c0)] = pk.u2;
                }
            }
        }
    }
    __syncthreads();

    // conv1b partials (static 6-iter unroll)
    #pragma unroll
    for (int it = 0; it < 6; it++) {
        int nt = wid + it * 4;
        if (nt < 21) {
            int p = nt * 16 + cl;
            int pc = p > 323 ? 323 : p;
            f16x8 bf0 = *(const f16x8*)&hid[swzoff(pc, gq * 8)];
            f16x8 bf1 = *(const f16x8*)&hid[swzoff(pc, 32 + gq * 8)];
            f32x4 z = {0.f, 0.f, 0.f, 0.f};
            f32x4 d = __builtin_amdgcn_mfma_f32_16x16x32_f16(afS0, bf0, z, 0, 0, 0);
            d = __builtin_amdgcn_mfma_f32_16x16x32_f16(afS1, bf1, d, 0, 0, 0);
            #pragma unroll
            for (int r = 0; r < 4; r++) {
                int tap = gq * 4 + r;
                if (tap < 9 && p < 324)
                    part[tap * 328 + p] = (f16)d[r];
            }
        }
    }
    __syncthreads();

    {
        int ty = tid >> 4, tx = tid & 15;
        float s = bscal;
        #pragma unroll
        for (int u = 0; u < 3; u++)
            #pragma unroll
            for (int v = 0; v < 3; v++)
                s += (float)part[(u * 3 + v) * 328 + (ty + u) * 18 + tx + v];
        feat[((size_t)(b * 2 + br)) * NPIX + (y0 + ty) * WW + x0 + tx] = s;
    }
}

// ---------------------------------------------------------------------------
// K2 v2: feat -> h1 (LDS, 18x18) -> h2 (HBM f16 [ci][pix][64]).
// wfb af operand now FRAGMENT-MAJOR from GLOBAL (pWbF): coalesced 1KB loads
// on the VMEM pipe, register double-buffered over tap-pairs -> wbufB and its
// 18 barriers DELETED; LDS pipe carries only bf (h1) reads.
// ---------------------------------------------------------------------------
__global__ __launch_bounds__(256, 3) void k2_wfab(
    const float* __restrict__ feat, const f16* __restrict__ pWa,
    const f16* __restrict__ pWbF, const float* __restrict__ bfa,
    const float* __restrict__ bfb, f16* __restrict__ h2g, int b0)
{
    __shared__ f16 ftt[800];      // [2][400] feat tile 20x20
    __shared__ f16 hid[20736];    // h1 [324][64] swz
    __shared__ float bA[64];
    __shared__ float bB[64];

    const int tid = threadIdx.x;
    const int wid = tid >> 6, lane = tid & 63;
    const int gq = lane >> 4, cl = lane & 15;
    const int x0 = blockIdx.x * 16, y0 = blockIdx.y * 16;
    const int ci = blockIdx.z, b = b0 + ci;

    for (int t = tid; t < 800; t += 256) {
        int cin = t / 400, p = t - 400 * cin;
        int r = p / 20, c = p - 20 * r;
        int gy = y0 - 2 + r, gx = x0 - 2 + c;
        ftt[t] = (f16)(((unsigned)gy < (unsigned)HH && (unsigned)gx < (unsigned)WW)
                           ? feat[((size_t)(b * 2 + cin)) * NPIX + gy * WW + gx] : 0.f);
    }
    if (tid < 64) { bA[tid] = bfa[tid]; bB[tid] = bfb[tid]; }

    int koff[8];
    #pragma unroll
    for (int j = 0; j < 8; j++) {
        int k = gq * 8 + j;
        int kc = k < 18 ? k : 0;
        int cin = kc >= 9 ? 1 : 0;
        int tap = kc - 9 * cin;
        koff[j] = cin * 400 + (tap / 3) * 20 + (tap % 3);
    }

    f16x8 afW[4];
    #pragma unroll
    for (int mt = 0; mt < 4; mt++)
        afW[mt] = *(const f16x8*)&pWa[(mt * 16 + cl) * 32 + gq * 8];
    __syncthreads();

    // wfa: h1 18x18 (static 6-iter unroll)
    #pragma unroll
    for (int it = 0; it < 6; it++) {
        int nt = wid + it * 4;
        if (nt < 21) {
            int p = nt * 16 + cl;
            int pc = p > 323 ? 323 : p;
            int py = pc / 18, px = pc - 18 * py;
            int base = py * 20 + px;
            f16x8 bf;
            #pragma unroll
            for (int j = 0; j < 8; j++) bf[j] = ftt[base + koff[j]];
            int gy = y0 - 1 + py, gx = x0 - 1 + px;
            bool ok = (p < 324) &&
                      ((unsigned)gy < (unsigned)HH && (unsigned)gx < (unsigned)WW);
            #pragma unroll
            for (int mt = 0; mt < 4; mt++) {
                f32x4 z = {0.f, 0.f, 0.f, 0.f};
                f32x4 acc = __builtin_amdgcn_mfma_f32_16x16x32_f16(afW[mt], bf, z, 0, 0, 0);
                if (p < 324) {
                    int c0 = mt * 16 + gq * 4;
                    union { f16 h[4]; uint2 u2; } pk;
                    #pragma unroll
                    for (int r = 0; r < 4; r++)
                        pk.h[r] = (f16)(ok ? fmaxf(acc[r] + bA[c0 + r], 0.f) : 0.f);
                    *(uint2*)&hid[swzoff(p, c0)] = pk.u2;
                }
            }
        }
    }
    __syncthreads();

    // wfb: barrier-free. af from global (fragment-major), reg double-buffer
    // over tap-pairs (kk0=2t shares u,v with kk1=2t+1).
    f32x4 acc[4][4];
    #pragma unroll
    for (int i = 0; i < 4; i++)
        #pragma unroll
        for (int mt = 0; mt < 4; mt++) acc[i][mt] = (f32x4){0.f, 0.f, 0.f, 0.f};

    const f16* wfp = pWbF + (size_t)lane * 8;   // frag (kk,mt) at +(kk*4+mt)*512
    f16x8 afA[4], afB[4];
    #pragma unroll
    for (int mt = 0; mt < 4; mt++)
        afA[mt] = *(const f16x8*)&wfp[mt * 512];

    #pragma unroll 1
    for (int kt = 0; kt < 9; kt++) {
        int u = kt / 3, v = kt - 3 * u;
        #pragma unroll
        for (int mt = 0; mt < 4; mt++)
            afB[mt] = *(const f16x8*)&wfp[((2 * kt + 1) * 4 + mt) * 512];
        // kk0 = 2*kt (cin half 0)
        #pragma unroll
        for (int i = 0; i < 4; i++) {
            int nt = wid * 4 + i;
            int hp = (nt + u) * 18 + cl + v;
            f16x8 bf = *(const f16x8*)&hid[swzoff(hp, gq * 8)];
            #pragma unroll
            for (int mt = 0; mt < 4; mt++)
                acc[i][mt] = __builtin_amdgcn_mfma_f32_16x16x32_f16(afA[mt], bf, acc[i][mt], 0, 0, 0);
        }
        if (kt < 8) {
            #pragma unroll
            for (int mt = 0; mt < 4; mt++)
                afA[mt] = *(const f16x8*)&wfp[((2 * kt + 2) * 4 + mt) * 512];
        }
        // kk1 = 2*kt+1 (cin half 1)
        #pragma unroll
        for (int i = 0; i < 4; i++) {
            int nt = wid * 4 + i;
            int hp = (nt + u) * 18 + cl + v;
            f16x8 bf = *(const f16x8*)&hid[swzoff(hp, 32 + gq * 8)];
            #pragma unroll
            for (int mt = 0; mt < 4; mt++)
                acc[i][mt] = __builtin_amdgcn_mfma_f32_16x16x32_f16(afB[mt], bf, acc[i][mt], 0, 0, 0);
        }
    }
    #pragma unroll
    for (int i = 0; i < 4; i++) {
        int nt = wid * 4 + i;                       // tile row; pixel col = cl
        size_t pb = ((size_t)ci * NPIX + (size_t)((y0 + nt) * WW + x0 + cl)) * 64;
        #pragma unroll
        for (int mt = 0; mt < 4; mt++) {
            int c0 = mt * 16 + gq * 4;
            union { f16 h[4]; uint2 u2; } pk;
            #pragma unroll
            for (int r = 0; r < 4; r++)
                pk.h[r] = (f16)fmaxf(acc[i][mt][r] + bB[c0 + r], 0.f);
            *(uint2*)&h2g[pb + c0] = pk.u2;
        }
    }
}

// ---------------------------------------------------------------------------
// K3 v4: h2 -> logits(96) -> softmax(81) -> patch apply -> out.
// Round-11 geometry (256 thr, acc[4][6]) but af from GLOBAL fragment-major
// (pWcF, coalesced 1KB loads, reg double-buffer over tap-pairs, unroll 1 so
// only 2 sets in flight — round-5/6 spill guard). wbufC DELETED -> kk loop
// has ZERO barriers; LDS pipe carries only bf reads. 44 KB LDS, 3 blocks/CU.
// Tripwire: WRITE_SIZE must stay ~4 MB (no spill).
// ---------------------------------------------------------------------------
__global__ __launch_bounds__(256, 3) void k3_wfc_apply(
    const f16* __restrict__ h2g, const f16* __restrict__ pWcF,
    const float* __restrict__ bfc, const float* __restrict__ x,
    float* __restrict__ out, int b0)
{
    __shared__ f16 h2t[20736];    // [324][64] swz
    __shared__ float xt24[576];   // 24x24
    __shared__ float bC[96];

    const int tid = threadIdx.x;
    const int wid = tid >> 6, lane = tid & 63;
    const int gq = lane >> 4, cl = lane & 15;
    const int x0 = blockIdx.x * 16, y0 = blockIdx.y * 16;
    const int ci = blockIdx.z, b = b0 + ci;

    for (int t = tid; t < 2592; t += 256) {
        int p = t >> 3, grp = t & 7;
        int py = p / 18, px = p - 18 * py;
        int gy = y0 - 1 + py, gx = x0 - 1 + px;
        f16x8 v = {};
        if ((unsigned)gy < (unsigned)HH && (unsigned)gx < (unsigned)WW)
            v = *(const f16x8*)&h2g[((size_t)ci * NPIX + (size_t)(gy * WW + gx)) * 64 + grp * 8];
        *(f16x8*)&h2t[swzoff(p, grp * 8)] = v;
    }
    const float* xb = x + (size_t)b * NPIX;
    for (int t = tid; t < 576; t += 256) {
        int r = t / 24, c = t - 24 * r;
        int gy = y0 - 4 + r, gx = x0 - 4 + c;
        xt24[t] = ((unsigned)gy < (unsigned)HH && (unsigned)gx < (unsigned)WW)
                      ? xb[gy * WW + gx] : 0.f;
    }
    if (tid < 96) bC[tid] = tid < 81 ? bfc[tid] : 0.f;
    __syncthreads();

    f32x4 acc[4][6];
    #pragma unroll
    for (int i = 0; i < 4; i++)
        #pragma unroll
        for (int mt = 0; mt < 6; mt++) acc[i][mt] = (f32x4){0.f, 0.f, 0.f, 0.f};

    const f16* wfp = pWcF + (size_t)lane * 8;   // frag (kk,mt) at +(kk*6+mt)*512
    f16x8 afA[6], afB[6];
    #pragma unroll
    for (int mt = 0; mt < 6; mt++)
        afA[mt] = *(const f16x8*)&wfp[mt * 512];

    #pragma unroll 1
    for (int kt = 0; kt < 9; kt++) {
        int u = kt / 3, v = kt - 3 * u;
        #pragma unroll
        for (int mt = 0; mt < 6; mt++)
            afB[mt] = *(const f16x8*)&wfp[((2 * kt + 1) * 6 + mt) * 512];
        // kk0 = 2*kt (cin half 0)
        #pragma unroll
        for (int i = 0; i < 4; i++) {
            int nt = wid * 4 + i;
            int hp = (nt + u) * 18 + cl + v;
            f16x8 bf = *(const f16x8*)&h2t[swzoff(hp, gq * 8)];
            #pragma unroll
            for (int mt = 0; mt < 6; mt++)
                acc[i][mt] = __builtin_amdgcn_mfma_f32_16x16x32_f16(afA[mt], bf, acc[i][mt], 0, 0, 0);
        }
        if (kt < 8) {
            #pragma unroll
            for (int mt = 0; mt < 6; mt++)
                afA[mt] = *(const f16x8*)&wfp[((2 * kt + 2) * 6 + mt) * 512];
        }
        // kk1 = 2*kt+1 (cin half 1)
        #pragma unroll
        for (int i = 0; i < 4; i++) {
            int nt = wid * 4 + i;
            int hp = (nt + u) * 18 + cl + v;
            f16x8 bf = *(const f16x8*)&h2t[swzoff(hp, 32 + gq * 8)];
            #pragma unroll
            for (int mt = 0; mt < 6; mt++)
                acc[i][mt] = __builtin_amdgcn_mfma_f32_16x16x32_f16(afB[mt], bf, acc[i][mt], 0, 0, 0);
        }
    }

    // softmax over taps (rows) for each pixel (col=cl); reduce across gq lanes
    #pragma unroll
    for (int i = 0; i < 4; i++) {
        int nt = wid * 4 + i;                       // pixel row; pixel col = cl
        float val[6][4];
        float m = -1e30f;
        #pragma unroll
        for (int mt = 0; mt < 6; mt++)
            #pragma unroll
            for (int r = 0; r < 4; r++) {
                int c = mt * 16 + gq * 4 + r;
                float vv = (c <= 80) ? acc[i][mt][r] + bC[c] : -1e30f;
                val[mt][r] = vv;
                m = fmaxf(m, vv);
            }
        m = fmaxf(m, __shfl_xor(m, 16));
        m = fmaxf(m, __shfl_xor(m, 32));
        float s = 0.f, o = 0.f;
        #pragma unroll
        for (int mt = 0; mt < 6; mt++)
            #pragma unroll
            for (int r = 0; r < 4; r++) {
                int c = mt * 16 + gq * 4 + r;
                if (c <= 80) {
                    float e = __expf(val[mt][r] - m);
                    int u9 = c / 9, v9 = c - 9 * u9;
                    s += e;
                    o += e * xt24[(nt + u9) * 24 + cl + v9];
                }
            }
        s += __shfl_xor(s, 16); s += __shfl_xor(s, 32);
        o += __shfl_xor(o, 16); o += __shfl_xor(o, 32);
        if (gq == 0)
            out[(size_t)b * NPIX + (y0 + nt) * WW + x0 + cl] = o / s;
    }
}

// ---------------------------------------------------------------------------
extern "C" void kernel_launch(void* const* d_in, const int* in_sizes, int n_in,
                              void* d_out, int out_size, void* d_ws, size_t ws_size,
                              hipStream_t stream)
{
    const float* x   = (const float*)d_in[0];
    const float* g   = (const float*)d_in[1];
    const float* w1a = (const float*)d_in[2];  const float* b1a = (const float*)d_in[3];
    const float* w1b = (const float*)d_in[4];  const float* b1b = (const float*)d_in[5];
    const float* w2a = (const float*)d_in[6];  const float* b2a = (const float*)d_in[7];
    const float* w2b = (const float*)d_in[8];  const float* b2b = (const float*)d_in[9];
    const float* wfa = (const float*)d_in[10]; const float* bfa = (const float*)d_in[11];
    const float* wfb = (const float*)d_in[12]; const float* bfb = (const float*)d_in[13];
    const float* wfc = (const float*)d_in[14]; const float* bfc = (const float*)d_in[15];
    float* out = (float*)d_out;

    // workspace: feat f32 | h2 chunk f16 | packed weights f16
    float* feat = (float*)d_ws;                       // 2,097,152 f32
    size_t featB = 2097152ull * 4;
    size_t pkB = 100352ull * 2;
    int nbc = 16;
    while (nbc > 1 && featB + (size_t)nbc * NPIX * 64 * 2 + pkB > ws_size) nbc >>= 1;

    f16* h2g = (f16*)((char*)d_ws + featB);
    f16* pk  = h2g + (size_t)nbc * NPIX * 64;
    f16* pA1  = pk;             // 2048
    f16* pA2  = pA1 + 2048;     // 2048
    f16* pWa  = pA2 + 2048;     // 2048
    f16* pBs1 = pWa + 2048;     // 1024
    f16* pBs2 = pBs1 + 1024;    // 1024
    f16* pWbF = pBs2 + 1024;    // 36864
    f16* pWcF = pWbF + 36864;   // 55296

    prepack_kernel<<<dim3(216), 256, 0, stream>>>(
        w1a, w2a, w1b, w2b, wfa, wfb, wfc, pA1, pA2, pWa, pBs1, pBs2, pWbF, pWcF);

    k1_branch<<<dim3(16, 16, 32), 256, 0, stream>>>(
        x, g, b1a, b2a, b1b, b2b, pA1, pA2, pBs1, pBs2, feat);

    for (int b0 = 0; b0 < NB; b0 += nbc) {
        int cn = (NB - b0) < nbc ? (NB - b0) : nbc;
        k2_wfab<<<dim3(16, 16, cn), 256, 0, stream>>>(
            feat, pWa, pWbF, bfa, bfb, h2g, b0);
        k3_wfc_apply<<<dim3(16, 16, cn), 256, 0, stream>>>(
            h2g, pWcF, bfc, x, out, b0);
    }
}